// Round 2
// baseline (5422.655 us; speedup 1.0000x reference)
//
#include <hip/hip_runtime.h>
#include <hip/hip_bf16.h>
#include <math.h>

// VRNN scan, R2: float4-packed fp32 weights in d_ws (lane-major), merged
// multi-stream inner loops. One wave per row, 4 rows/block, 256 blocks.
// eps ~= 0 approximation unchanged (passed R1).

#define HD    64
#define TT    128
#define NZN   5
#define ADIM  20

// packed-weight offsets in d_ws (floats)
#define OFF_X   0        // W_x    [32][64]f4
#define OFF_P1  8192     // Wp1    [160][64]f4 (5*32 row-quads)
#define OFF_P2  49152    // Wp2    [80][64]f4
#define OFF_Q1  69632    // Wq1    [80][64]f4
#define OFF_Q2  90112    // Wq2    [80][64]f4
#define OFF_Z   110592   // W_z    [16][64]f4
#define OFF_IH  114688   // W_ih   [96][64]f4  ((i4*3+g) rows)
#define OFF_HH  139264   // W_hh   [48][64]f4
#define OFF_D   151552   // W_dec  [32][64]f4
#define WS_FLOATS 159744

__device__ __forceinline__ float reluf(float x) { return fmaxf(x, 0.f); }
__device__ __forceinline__ float softplusf(float x) {
    return fmaxf(x, 0.f) + log1pf(expf(-fabsf(x)));
}
__device__ __forceinline__ float sigmoidf_(float x) { return 1.f / (1.f + expf(-x)); }
__device__ __forceinline__ float dot4(float acc, float4 a, float4 w) {
    acc = fmaf(a.x, w.x, acc); acc = fmaf(a.y, w.y, acc);
    acc = fmaf(a.z, w.z, acc); acc = fmaf(a.w, w.w, acc);
    return acc;
}
__device__ __forceinline__ float wave_sum64(float v) {
#pragma unroll
    for (int off = 32; off > 0; off >>= 1) v += __shfl_xor(v, off, 64);
    return v;
}
__device__ __forceinline__ float4 ldsf4(const float* p) {
    return *(const float4*)p;
}

__global__ void vrnn_zero(float* out) { out[22528] = 0.f; }

// Repack weights: dest[((i4*64+ln)*4+k)] = src[(4*i4+k)*ldcols + col]
__global__ __launch_bounds__(256) void vrnn_pack(
    const float* __restrict__ W_x,  const float* __restrict__ Wp1,
    const float* __restrict__ Wp2,  const float* __restrict__ Wq1,
    const float* __restrict__ Wq2,  const float* __restrict__ W_z,
    const float* __restrict__ W_ih, const float* __restrict__ W_hh,
    const float* __restrict__ W_dec, float* __restrict__ ws)
{
    const int tid = blockIdx.x * blockDim.x + threadIdx.x;
    const int NT  = gridDim.x * blockDim.x;
    // simple [R][64] matrices (R rows, 64 cols): flat-row packing
    for (int e = tid; e < 8192; e += NT) {           // W_x R=128
        int k = e & 3, ln = (e >> 2) & 63, i4 = e >> 8;
        ws[OFF_X + e] = W_x[(4 * i4 + k) * 64 + ln];
    }
    for (int e = tid; e < 40960; e += NT) {          // Wp1 R=640
        int k = e & 3, ln = (e >> 2) & 63, i4 = e >> 8;
        ws[OFF_P1 + e] = Wp1[(4 * i4 + k) * 64 + ln];
    }
    for (int e = tid; e < 20480; e += NT) {          // Wp2 R=320
        int k = e & 3, ln = (e >> 2) & 63, i4 = e >> 8;
        ws[OFF_P2 + e] = Wp2[(4 * i4 + k) * 64 + ln];
    }
    for (int e = tid; e < 20480; e += NT) {          // Wq1 R=320
        int k = e & 3, ln = (e >> 2) & 63, i4 = e >> 8;
        ws[OFF_Q1 + e] = Wq1[(4 * i4 + k) * 64 + ln];
    }
    for (int e = tid; e < 20480; e += NT) {          // Wq2 R=320
        int k = e & 3, ln = (e >> 2) & 63, i4 = e >> 8;
        ws[OFF_Q2 + e] = Wq2[(4 * i4 + k) * 64 + ln];
    }
    for (int e = tid; e < 4096; e += NT) {           // W_z R=64
        int k = e & 3, ln = (e >> 2) & 63, i4 = e >> 8;
        ws[OFF_Z + e] = W_z[(4 * i4 + k) * 64 + ln];
    }
    for (int e = tid; e < 24576; e += NT) {          // W_ih [128][192]
        int k = e & 3, ln = (e >> 2) & 63, gg = (e >> 8);
        int g = gg % 3, i4 = gg / 3;
        ws[OFF_IH + e] = W_ih[(4 * i4 + k) * 192 + g * 64 + ln];
    }
    for (int e = tid; e < 12288; e += NT) {          // W_hh [64][192]
        int k = e & 3, ln = (e >> 2) & 63, gg = (e >> 8);
        int g = gg % 3, i4 = gg / 3;
        ws[OFF_HH + e] = W_hh[(4 * i4 + k) * 192 + g * 64 + ln];
    }
    for (int e = tid; e < 8192; e += NT) {           // W_dec R=128
        int k = e & 3, ln = (e >> 2) & 63, i4 = e >> 8;
        ws[OFF_D + e] = W_dec[(4 * i4 + k) * 64 + ln];
    }
}

__global__ __launch_bounds__(256, 1) void vrnn_main(
    const int* __restrict__ acts, const float* __restrict__ durs,
    const float* __restrict__ W_act, const float* __restrict__ b_act,
    const float* __restrict__ W_dur, const float* __restrict__ b_dur,
    const float* __restrict__ b_x, const float* __restrict__ b_z,
    const float* __restrict__ bp1, const float* __restrict__ bp2,
    const float* __restrict__ bq1, const float* __restrict__ bq2,
    const float* __restrict__ Wq1, const float* __restrict__ Wq2,
    const float* __restrict__ W_z, const float* __restrict__ W_dec,
    const float* __restrict__ b_dec,
    const float* __restrict__ W_a, const float* __restrict__ b_a,
    const float* __restrict__ W_durd, const float* __restrict__ b_durd,
    const float* __restrict__ b_ih, const float* __restrict__ b_hh,
    const float* __restrict__ g_post, const float* __restrict__ g_prior,
    const float* __restrict__ ws, float* __restrict__ d_out)
{
    const int wv  = threadIdx.x >> 6;
    const int ln  = threadIdx.x & 63;
    const int row = (blockIdx.x << 2) + wv;

    __shared__ float s_inp[4][128];      // [phi_act,phi_dur] -> [phi_x,h]
    __shared__ float s_hpb[4][NZN * 64]; // posterior hidden
    __shared__ float s_hqb[4][NZN * 64]; // prior hidden
    __shared__ float s_ax[4][64];        // pm -> phi_z

    float* s_in = s_inp[wv];
    float* s_hp = s_hpb[wv];
    float* s_hq = s_hqb[wv];
    float* s_a  = s_ax[wv];

    const float4* Xp  = (const float4*)(ws + OFF_X);
    const float4* P1p = (const float4*)(ws + OFF_P1);
    const float4* P2p = (const float4*)(ws + OFF_P2);
    const float4* Q1p = (const float4*)(ws + OFF_Q1);
    const float4* Q2p = (const float4*)(ws + OFF_Q2);
    const float4* Zp  = (const float4*)(ws + OFF_Z);
    const float4* IHp = (const float4*)(ws + OFF_IH);
    const float4* HHp = (const float4*)(ws + OFF_HH);

    float h     = 0.f;
    float klacc = 0.f;

    float gp[NZN], gq[NZN], bp1r[NZN], bq1r[NZN], bp2r[NZN], bq2r[NZN];
#pragma unroll
    for (int n = 0; n < NZN; ++n) {
        gp[n]   = g_post[n];        gq[n]   = g_prior[n];
        bp1r[n] = bp1[n * 64 + ln]; bq1r[n] = bq1[n * 64 + ln];
        bp2r[n] = bp2[n * 64 + ln]; bq2r[n] = bq2[n * 64 + ln];
    }
    const float bact = b_act[ln];
    const float wdur = W_dur[ln];
    const float bdur = b_dur[ln];
    const float bx   = b_x[ln];
    const float bz   = b_z[ln];
    const float bih0 = b_ih[ln], bih1 = b_ih[64 + ln], bih2 = b_ih[128 + ln];
    const float bhh0 = b_hh[ln], bhh1 = b_hh[64 + ln], bhh2 = b_hh[128 + ln];

    for (int t = 0; t < TT; ++t) {
        const int   a   = acts[row * TT + t];
        const float dur = durs[row * TT + t];
        const float pa  = reluf(W_act[a * HD + ln] + bact);
        const float pd  = reluf(dur * wdur + bdur);

        __syncthreads();                       // prev GRU reads done
        s_in[ln]      = pa;
        s_in[64 + ln] = pd;
        __syncthreads();

        // ---- phi_x
        float x0 = 0.f, x1 = 0.f;
#pragma unroll
        for (int i4 = 0; i4 < 16; ++i4) {
            float4 a0 = ldsf4(&s_in[i4 * 4]);
            float4 a1 = ldsf4(&s_in[64 + i4 * 4]);
            x0 = dot4(x0, a0, Xp[i4 * 64 + ln]);
            x1 = dot4(x1, a1, Xp[(16 + i4) * 64 + ln]);
        }
        const float phix = reluf(x0 + x1 + bx);

        __syncthreads();
        s_in[ln]      = phix;
        s_in[64 + ln] = h;
        __syncthreads();

        // ---- merged layer1: posterior (K=128) + prior (K=64, upper half)
        float p0 = bp1r[0], p1 = bp1r[1], p2 = bp1r[2], p3 = bp1r[3], p4 = bp1r[4];
        float q0 = bq1r[0], q1 = bq1r[1], q2 = bq1r[2], q3 = bq1r[3], q4 = bq1r[4];
#pragma unroll 4
        for (int i4 = 0; i4 < 16; ++i4) {
            float4 a0 = ldsf4(&s_in[i4 * 4]);
            p0 = dot4(p0, a0, P1p[(0 * 32 + i4) * 64 + ln]);
            p1 = dot4(p1, a0, P1p[(1 * 32 + i4) * 64 + ln]);
            p2 = dot4(p2, a0, P1p[(2 * 32 + i4) * 64 + ln]);
            p3 = dot4(p3, a0, P1p[(3 * 32 + i4) * 64 + ln]);
            p4 = dot4(p4, a0, P1p[(4 * 32 + i4) * 64 + ln]);
        }
#pragma unroll 2
        for (int i4 = 0; i4 < 16; ++i4) {
            float4 a1 = ldsf4(&s_in[64 + i4 * 4]);
            p0 = dot4(p0, a1, P1p[(0 * 32 + 16 + i4) * 64 + ln]);
            p1 = dot4(p1, a1, P1p[(1 * 32 + 16 + i4) * 64 + ln]);
            p2 = dot4(p2, a1, P1p[(2 * 32 + 16 + i4) * 64 + ln]);
            p3 = dot4(p3, a1, P1p[(3 * 32 + 16 + i4) * 64 + ln]);
            p4 = dot4(p4, a1, P1p[(4 * 32 + 16 + i4) * 64 + ln]);
            q0 = dot4(q0, a1, Q1p[(0 * 16 + i4) * 64 + ln]);
            q1 = dot4(q1, a1, Q1p[(1 * 16 + i4) * 64 + ln]);
            q2 = dot4(q2, a1, Q1p[(2 * 16 + i4) * 64 + ln]);
            q3 = dot4(q3, a1, Q1p[(3 * 16 + i4) * 64 + ln]);
            q4 = dot4(q4, a1, Q1p[(4 * 16 + i4) * 64 + ln]);
        }
        s_hp[0 * 64 + ln] = reluf(p0); s_hp[1 * 64 + ln] = reluf(p1);
        s_hp[2 * 64 + ln] = reluf(p2); s_hp[3 * 64 + ln] = reluf(p3);
        s_hp[4 * 64 + ln] = reluf(p4);
        s_hq[0 * 64 + ln] = reluf(q0); s_hq[1 * 64 + ln] = reluf(q1);
        s_hq[2 * 64 + ln] = reluf(q2); s_hq[3 * 64 + ln] = reluf(q3);
        s_hq[4 * 64 + ln] = reluf(q4);
        __syncthreads();

        // ---- merged layer2 (10 streams)
        float c0 = bp2r[0], c1 = bp2r[1], c2 = bp2r[2], c3 = bp2r[3], c4 = bp2r[4];
        float d0 = bq2r[0], d1 = bq2r[1], d2 = bq2r[2], d3 = bq2r[3], d4 = bq2r[4];
#pragma unroll 2
        for (int i4 = 0; i4 < 16; ++i4) {
            c0 = dot4(c0, ldsf4(&s_hp[0 * 64 + i4 * 4]), P2p[(0 * 16 + i4) * 64 + ln]);
            c1 = dot4(c1, ldsf4(&s_hp[1 * 64 + i4 * 4]), P2p[(1 * 16 + i4) * 64 + ln]);
            c2 = dot4(c2, ldsf4(&s_hp[2 * 64 + i4 * 4]), P2p[(2 * 16 + i4) * 64 + ln]);
            c3 = dot4(c3, ldsf4(&s_hp[3 * 64 + i4 * 4]), P2p[(3 * 16 + i4) * 64 + ln]);
            c4 = dot4(c4, ldsf4(&s_hp[4 * 64 + i4 * 4]), P2p[(4 * 16 + i4) * 64 + ln]);
            d0 = dot4(d0, ldsf4(&s_hq[0 * 64 + i4 * 4]), Q2p[(0 * 16 + i4) * 64 + ln]);
            d1 = dot4(d1, ldsf4(&s_hq[1 * 64 + i4 * 4]), Q2p[(1 * 16 + i4) * 64 + ln]);
            d2 = dot4(d2, ldsf4(&s_hq[2 * 64 + i4 * 4]), Q2p[(2 * 16 + i4) * 64 + ln]);
            d3 = dot4(d3, ldsf4(&s_hq[3 * 64 + i4 * 4]), Q2p[(3 * 16 + i4) * 64 + ln]);
            d4 = dot4(d4, ldsf4(&s_hq[4 * 64 + i4 * 4]), Q2p[(4 * 16 + i4) * 64 + ln]);
        }
        const float mpost = gp[0] * c0 + gp[1] * c1 + gp[2] * c2 + gp[3] * c3 + gp[4] * c4;
        const float mpri  = gq[0] * d0 + gq[1] * d1 + gq[2] * d2 + gq[3] * d3 + gq[4] * d4;
        const float pm = reluf(mpost), ps = softplusf(mpost);
        const float qm = reluf(mpri),  qs = softplusf(mpri);
        {
            const float dd = pm - qm;
            klacc += logf(qs / ps) + (ps * ps + dd * dd) / (2.f * qs * qs) - 0.5f;
        }

        __syncthreads();
        s_a[ln] = pm;                          // z = pm (eps ~= 0)
        __syncthreads();

        // ---- phi_z
        float z0 = 0.f, z1 = 0.f;
#pragma unroll
        for (int i4 = 0; i4 < 8; ++i4) {
            z0 = dot4(z0, ldsf4(&s_a[i4 * 4]),      Zp[i4 * 64 + ln]);
            z1 = dot4(z1, ldsf4(&s_a[32 + i4 * 4]), Zp[(8 + i4) * 64 + ln]);
        }
        const float phiz = reluf(z0 + z1 + bz);
        __syncthreads();
        s_a[ln] = phiz;
        __syncthreads();

        // ---- GRU (x = [phix, phiz], h) : 6 streams, 9 loads/iter
        float i0 = bih0, i1 = bih1, i2 = bih2;
        float g0 = bhh0, g1 = bhh1, g2 = bhh2;
#pragma unroll 2
        for (int i4 = 0; i4 < 16; ++i4) {
            float4 ax = ldsf4(&s_in[i4 * 4]);
            float4 ah = ldsf4(&s_in[64 + i4 * 4]);
            float4 az = ldsf4(&s_a[i4 * 4]);
            i0 = dot4(i0, ax, IHp[(i4 * 3 + 0) * 64 + ln]);
            i1 = dot4(i1, ax, IHp[(i4 * 3 + 1) * 64 + ln]);
            i2 = dot4(i2, ax, IHp[(i4 * 3 + 2) * 64 + ln]);
            i0 = dot4(i0, az, IHp[((16 + i4) * 3 + 0) * 64 + ln]);
            i1 = dot4(i1, az, IHp[((16 + i4) * 3 + 1) * 64 + ln]);
            i2 = dot4(i2, az, IHp[((16 + i4) * 3 + 2) * 64 + ln]);
            g0 = dot4(g0, ah, HHp[(i4 * 3 + 0) * 64 + ln]);
            g1 = dot4(g1, ah, HHp[(i4 * 3 + 1) * 64 + ln]);
            g2 = dot4(g2, ah, HHp[(i4 * 3 + 2) * 64 + ln]);
        }
        const float rr = sigmoidf_(i0 + g0);
        const float zz = sigmoidf_(i1 + g1);
        const float nn = tanhf(i2 + rr * g2);
        h = (1.f - zz) * nn + zz * h;
    }

    // ================= final decode (once; unpacked weights fine) ==========
    __syncthreads();
    s_in[64 + ln] = h;
    __syncthreads();

    float r0 = bq1r[0], r1 = bq1r[1], r2 = bq1r[2], r3 = bq1r[3], r4 = bq1r[4];
#pragma unroll 4
    for (int i = 0; i < 64; ++i) {
        const float v = s_in[64 + i];
        r0 += v * Wq1[(0 * 64 + i) * HD + ln];
        r1 += v * Wq1[(1 * 64 + i) * HD + ln];
        r2 += v * Wq1[(2 * 64 + i) * HD + ln];
        r3 += v * Wq1[(3 * 64 + i) * HD + ln];
        r4 += v * Wq1[(4 * 64 + i) * HD + ln];
    }
    s_hq[0 * 64 + ln] = reluf(r0);
    s_hq[1 * 64 + ln] = reluf(r1);
    s_hq[2 * 64 + ln] = reluf(r2);
    s_hq[3 * 64 + ln] = reluf(r3);
    s_hq[4 * 64 + ln] = reluf(r4);
    __syncthreads();
    float u0 = bq2r[0], u1 = bq2r[1], u2 = bq2r[2], u3 = bq2r[3], u4 = bq2r[4];
#pragma unroll 4
    for (int o = 0; o < 64; ++o) {
        u0 += s_hq[0 * 64 + o] * Wq2[(0 * 64 + o) * HD + ln];
        u1 += s_hq[1 * 64 + o] * Wq2[(1 * 64 + o) * HD + ln];
        u2 += s_hq[2 * 64 + o] * Wq2[(2 * 64 + o) * HD + ln];
        u3 += s_hq[3 * 64 + o] * Wq2[(3 * 64 + o) * HD + ln];
        u4 += s_hq[4 * 64 + o] * Wq2[(4 * 64 + o) * HD + ln];
    }
    const float mpri = gq[0] * u0 + gq[1] * u1 + gq[2] * u2 + gq[3] * u3 + gq[4] * u4;
    const float z = reluf(mpri);

    s_a[ln] = z;
    __syncthreads();
    float z0 = 0.f, z1 = 0.f;
#pragma unroll 8
    for (int i = 0; i < 32; ++i) {
        z0 += s_a[i]      * W_z[i * HD + ln];
        z1 += s_a[32 + i] * W_z[(32 + i) * HD + ln];
    }
    const float phiz = reluf(z0 + z1 + bz);
    __syncthreads();
    s_in[ln] = phiz;
    __syncthreads();

    float a0 = 0.f, a1 = 0.f;
#pragma unroll 8
    for (int i = 0; i < 64; ++i) {
        a0 += s_in[i]      * W_dec[i * HD + ln];
        a1 += s_in[64 + i] * W_dec[(64 + i) * HD + ln];
    }
    const float dec = reluf(a0 + a1 + b_dec[ln]);

    __syncthreads();
    s_hp[ln] = dec;
    __syncthreads();

    float lg = 0.f;
    if (ln < ADIM) {
        lg = b_a[ln];
#pragma unroll 8
        for (int o = 0; o < 64; ++o) lg += s_hp[o] * W_a[o * ADIM + ln];
        d_out[row * ADIM + ln] = lg;
    }
    __syncthreads();
    if (ln < ADIM) s_a[ln] = lg;
    __syncthreads();

    float pl = bact;
#pragma unroll
    for (int j = 0; j < ADIM; ++j) pl += s_a[j] * W_act[j * HD + ln];
    pl = reluf(pl);

    float contrib = pl * W_durd[ln] + dec * W_durd[64 + ln];
    contrib = wave_sum64(contrib);
    const float kls = wave_sum64(klacc);

    if (ln == 0) {
        const float dd = contrib + b_durd[0];
        d_out[20480 + row] = dd;
        d_out[21504 + row] = softplusf(dd);
        atomicAdd(d_out + 22528, kls * (1.f / 1024.f));
    }
}

extern "C" void kernel_launch(void* const* d_in, const int* in_sizes, int n_in,
                              void* d_out, int out_size, void* d_ws, size_t ws_size,
                              hipStream_t stream)
{
    const int*   acts    = (const int*)  d_in[0];
    const float* durs    = (const float*)d_in[1];
    const float* W_act   = (const float*)d_in[2];
    const float* b_act   = (const float*)d_in[3];
    const float* W_dur   = (const float*)d_in[4];
    const float* b_dur   = (const float*)d_in[5];
    const float* W_x     = (const float*)d_in[6];
    const float* b_x     = (const float*)d_in[7];
    const float* W_z     = (const float*)d_in[8];
    const float* b_z     = (const float*)d_in[9];
    const float* Wp1     = (const float*)d_in[10];
    const float* bp1     = (const float*)d_in[11];
    const float* Wp2     = (const float*)d_in[12];
    const float* bp2     = (const float*)d_in[13];
    const float* Wq1     = (const float*)d_in[14];
    const float* bq1     = (const float*)d_in[15];
    const float* Wq2     = (const float*)d_in[16];
    const float* bq2     = (const float*)d_in[17];
    const float* W_dec   = (const float*)d_in[18];
    const float* b_dec   = (const float*)d_in[19];
    const float* W_a     = (const float*)d_in[20];
    const float* b_a     = (const float*)d_in[21];
    const float* W_durd  = (const float*)d_in[22];
    const float* b_durd  = (const float*)d_in[23];
    const float* W_ih    = (const float*)d_in[24];
    const float* W_hh    = (const float*)d_in[25];
    const float* b_ih    = (const float*)d_in[26];
    const float* b_hh    = (const float*)d_in[27];
    const float* g_post  = (const float*)d_in[28];
    const float* g_prior = (const float*)d_in[29];
    float* out = (float*)d_out;
    float* ws  = (float*)d_ws;

    vrnn_zero<<<1, 1, 0, stream>>>(out);
    vrnn_pack<<<160, 256, 0, stream>>>(W_x, Wp1, Wp2, Wq1, Wq2, W_z, W_ih, W_hh,
                                       W_dec, ws);
    vrnn_main<<<256, 256, 0, stream>>>(
        acts, durs, W_act, b_act, W_dur, b_dur, b_x, b_z,
        bp1, bp2, bq1, bq2, Wq1, Wq2, W_z, W_dec, b_dec,
        W_a, b_a, W_durd, b_durd, b_ih, b_hh, g_post, g_prior,
        ws, out);
}